// Round 15
// baseline (245.830 us; speedup 1.0000x reference)
//
#include <hip/hip_runtime.h>
#include <hip/hip_bf16.h>

#define HEADS 8
#define HID 256
#define NA 10000
#define NPAP 20000
#define NE 256000
#define N_SEG (2 * NPAP + NA)     // combined segments: writes(20k) | cites(20k) | rev(10k)
#define TOTE (3 * NE)             // combined edges
#define NEG_SLOPE 0.2f
#define NBA 157                   // (NA+63)/64
#define NBP 313                   // (NPAP+63)/64
#define PROJ_BLKS (4 * (NBA + NBP))   // 1880 (64x64 tiles, 4 col-quadrants)
#define DEG_BLKS 3000             // TOTE/256
#define NATT_BLKS (NPAP + NA)     // 30000
#define NBS ((N_SEG + 255) / 256) // 196

typedef __attribute__((ext_vector_type(8))) short bf16x8;
typedef __attribute__((ext_vector_type(4))) float f32x4;

// ---------- f32 <-> bf16 helpers ----------
__device__ __forceinline__ short f2bf(float x) {
    unsigned u = __float_as_uint(x);
    unsigned r = (u + 0x7fffu + ((u >> 16) & 1u)) >> 16;   // RNE
    return (short)r;
}
__device__ __forceinline__ float bf2f(short s) {
    return __uint_as_float(((unsigned)(unsigned short)s) << 16);
}

// ---------- weight transposes: Wt[c][k] = bf16(W[k][c]) ----------
__global__ __launch_bounds__(256) void wconv(
    const float* __restrict__ W_a, short* __restrict__ WaT,
    const float* __restrict__ W_p, short* __restrict__ WpT,
    const float* __restrict__ k_W, short* __restrict__ kWT)
{
    __shared__ short T[64][65];
    int b = blockIdx.x;
    int t = threadIdx.x;
    int z = b >> 4, rem = b & 15;
    int k0 = (rem & 3) * 64, c0 = (rem >> 2) * 64;
    const float* W = z == 0 ? W_a : (z == 1 ? W_p : k_W);
    short* Wt      = z == 0 ? WaT : (z == 1 ? WpT : kWT);
    int rr = t >> 6, c = t & 63;
#pragma unroll
    for (int p = 0; p < 16; ++p) {
        int r = rr + p * 4;
        T[c][r] = f2bf(W[(size_t)(k0 + r) * 256 + c0 + c]);
    }
    __syncthreads();
#pragma unroll
    for (int p = 0; p < 16; ++p) {
        int cc = rr + p * 4;
        Wt[(size_t)(c0 + cc) * 256 + k0 + c] = T[cc][c];
    }
}

// ---------- fused: projection GEMMs (64x64 tiles, 16KB LDS) ∪ deg-count+rank ----------
// Small LDS keeps deg-region occupancy high; atomics hide under MFMA blocks.
// shadow(e) = (e>>8)&3 — matches scatter_edges.
__global__ __launch_bounds__(256) void proj_deg(
    const float* __restrict__ A0, const short* __restrict__ Wt0, const float* __restrict__ b0,
    short* __restrict__ C0, unsigned char* __restrict__ H80,
    const float* __restrict__ A1, const short* __restrict__ Wt1, const float* __restrict__ b1,
    short* __restrict__ C1, unsigned char* __restrict__ H81,
    const int* __restrict__ ewd, const int* __restrict__ ecd, const int* __restrict__ erd,
    int* __restrict__ deg4, unsigned short* __restrict__ rank16)
{
    __shared__ short As[64][64];
    __shared__ short Ws2[64][64];

    int b = blockIdx.x;
    int t = threadIdx.x;

    if (b >= PROJ_BLKS) {
        // ---- deg + rank region (LDS unused; 16KB reservation keeps occupancy high) ----
        int bb = b - PROJ_BLKS;
        int e = bb * 256 + t;
        if (e >= TOTE) return;
        int d;
        if (e < NE)          d = ewd[e];
        else if (e < 2 * NE) d = ecd[e - NE] + NPAP;
        else                 d = erd[e - 2 * NE] + 2 * NPAP;
        int r = atomicAdd(&deg4[(bb & 3) * N_SEG + d], 1);
        rank16[e] = (unsigned short)r;
        return;
    }

    // ---- projection GEMM region: 64 rows x 64 cols per block ----
    const float* A; const short* Wt; const float* bias; short* Cb; unsigned char* H8; int N, row0, col0;
    if (b < 4 * NBA) { A = A0; Wt = Wt0; bias = b0; Cb = C0; H8 = H80; N = NA;
                       row0 = (b >> 2) * 64; col0 = (b & 3) * 64; }
    else             { int bb = b - 4 * NBA;
                       A = A1; Wt = Wt1; bias = b1; Cb = C1; H8 = H81; N = NPAP;
                       row0 = (bb >> 2) * 64; col0 = (bb & 3) * 64; }

    int w = t >> 6, l = t & 63;
    int lr = l & 15, lh = l >> 4;
    int swz = (l & 7) << 3;

    f32x4 acc[4] = {};   // wave w: rows [w*16, w*16+16), cols [0,64) of tile

    for (int k0 = 0; k0 < 256; k0 += 64) {
        // stage A: 64 rows x 64 k, f32 -> bf16 in-register
#pragma unroll
        for (int i = 0; i < 4; ++i) {
            int lin = t + i * 256;
            int r = lin >> 4, fc = (lin & 15) << 2;
            float4 v = make_float4(0.f, 0.f, 0.f, 0.f);
            int gr = row0 + r;
            if (gr < N) v = *reinterpret_cast<const float4*>(&A[(size_t)gr * 256 + k0 + fc]);
            short4 o;
            o.x = f2bf(v.x); o.y = f2bf(v.y); o.z = f2bf(v.z); o.w = f2bf(v.w);
            *reinterpret_cast<short4*>(&As[r][fc ^ ((r & 7) << 3)]) = o;
        }
        // stage W quadrant: 64 cols x 64 k
#pragma unroll
        for (int i = 0; i < 2; ++i) {
            int lin = t + i * 256;
            int c = lin >> 3, kc = (lin & 7) << 3;
            *reinterpret_cast<bf16x8*>(&Ws2[c][kc ^ ((c & 7) << 3)]) =
                *reinterpret_cast<const bf16x8*>(&Wt[(size_t)(col0 + c) * 256 + k0 + kc]);
        }
        __syncthreads();
#pragma unroll
        for (int kk = 0; kk < 64; kk += 32) {
            int krow = (kk + lh * 8) ^ swz;
            bf16x8 af = *reinterpret_cast<bf16x8*>(&As[w * 16 + lr][krow]);
            bf16x8 bfr[4];
#pragma unroll
            for (int ni = 0; ni < 4; ++ni)
                bfr[ni] = *reinterpret_cast<bf16x8*>(&Ws2[ni * 16 + lr][krow]);
#pragma unroll
            for (int ni = 0; ni < 4; ++ni)
                acc[ni] = __builtin_amdgcn_mfma_f32_16x16x32_bf16(af, bfr[ni], acc[ni], 0, 0, 0);
        }
        __syncthreads();
    }

    int rb = row0 + w * 16 + lh * 4;
#pragma unroll
    for (int ni = 0; ni < 4; ++ni) {
        int c = col0 + ni * 16 + lr;
        float bc = bias[c];
#pragma unroll
        for (int j = 0; j < 4; ++j) {
            if (rb + j < N) {
                float v = acc[ni][j] + bc;
                Cb[(size_t)(rb + j) * 256 + c] = f2bf(v);
                unsigned pk = __builtin_amdgcn_cvt_pk_fp8_f32(v, v, 0, false);
                H8[(size_t)(rb + j) * 256 + c] = (unsigned char)pk;
            }
        }
    }
}

// ---------- fused: per-node attention dots ∪ scan level-1 ----------
__global__ __launch_bounds__(256) void natt_scan(
    const short* __restrict__ h_p, const short* __restrict__ h_a,
    const float* __restrict__ att_dw, const float* __restrict__ att_sc,
    const float* __restrict__ att_dc, const float* __restrict__ att_sr,
    const float* __restrict__ att_sw, const float* __restrict__ att_dr,
    float* __restrict__ a_dw, float* __restrict__ a_sc,
    float* __restrict__ a_dc, float* __restrict__ a_sr,
    float* __restrict__ a_sw, float* __restrict__ a_dr,
    const int* __restrict__ deg4, int* __restrict__ excl, int* __restrict__ bsum)
{
    int b = blockIdx.x;
    int t = threadIdx.x;

    if (b >= NATT_BLKS) {
        __shared__ int buf[256];
        int bb = b - NATT_BLKS;
        int idx = bb * 256 + t;
        int v = 0;
        if (idx < N_SEG)
            v = deg4[idx] + deg4[N_SEG + idx] + deg4[2 * N_SEG + idx] + deg4[3 * N_SEG + idx];
        buf[t] = v;
        __syncthreads();
        for (int off = 1; off < 256; off <<= 1) {
            int add = (t >= off) ? buf[t - off] : 0;
            __syncthreads();
            buf[t] += add;
            __syncthreads();
        }
        if (idx < N_SEG) excl[idx] = buf[t] - v;
        if (t == 255) bsum[bb] = buf[255];
        return;
    }

    if (b < NPAP) {
        float v = bf2f(h_p[(size_t)b * 256 + t]);
        float d0 = v * att_dw[t], d1 = v * att_sc[t], d2 = v * att_dc[t], d3 = v * att_sr[t];
#pragma unroll
        for (int k = 16; k > 0; k >>= 1) {
            d0 += __shfl_xor(d0, k, 64);
            d1 += __shfl_xor(d1, k, 64);
            d2 += __shfl_xor(d2, k, 64);
            d3 += __shfl_xor(d3, k, 64);
        }
        if ((t & 31) == 0) {
            int hh = t >> 5;
            a_dw[b * 8 + hh] = d0; a_sc[b * 8 + hh] = d1;
            a_dc[b * 8 + hh] = d2; a_sr[b * 8 + hh] = d3;
        }
    } else {
        int m = b - NPAP;
        float v = bf2f(h_a[(size_t)m * 256 + t]);
        float d0 = v * att_sw[t], d1 = v * att_dr[t];
#pragma unroll
        for (int k = 16; k > 0; k >>= 1) {
            d0 += __shfl_xor(d0, k, 64);
            d1 += __shfl_xor(d1, k, 64);
        }
        if ((t & 31) == 0) {
            int hh = t >> 5;
            a_sw[m * 8 + hh] = d0; a_dr[m * 8 + hh] = d1;
        }
    }
}

// ---------- scan level-2 ----------
__global__ void scan_l2(const int* __restrict__ bsum, int* __restrict__ boff, int nb)
{
    __shared__ int buf[256];
    int t = threadIdx.x;
    int v = (t < nb) ? bsum[t] : 0;
    buf[t] = v;
    __syncthreads();
    for (int off = 1; off < 256; off <<= 1) {
        int add = (t >= off) ? buf[t - off] : 0;
        __syncthreads();
        buf[t] += add;
        __syncthreads();
    }
    if (t < nb) boff[t] = buf[t] - v;
}

// L3: starts + 4 shadow bases
__global__ void scan_l3(const int* __restrict__ excl, const int* __restrict__ boff,
                        const int* __restrict__ deg4,
                        int* __restrict__ starts, int* __restrict__ base4, int N)
{
    int i = blockIdx.x * 256 + threadIdx.x;
    if (i > N) return;
    int v = (i == N) ? TOTE : excl[i] + boff[i >> 8];
    starts[i] = v;
    if (i < N) {
        int c = v;
        base4[i] = c;                 c += deg4[i];
        base4[N_SEG + i] = c;         c += deg4[N_SEG + i];
        base4[2 * N_SEG + i] = c;     c += deg4[2 * N_SEG + i];
        base4[3 * N_SEG + i] = c;
    }
}

// ---------- edge scatter: NO atomics ----------
__global__ __launch_bounds__(256) void scatter_edges(
    const int* __restrict__ ews, const int* __restrict__ ewd,
    const int* __restrict__ ecs, const int* __restrict__ ecd,
    const int* __restrict__ ers, const int* __restrict__ erd,
    const int* __restrict__ base4, const unsigned short* __restrict__ rank16,
    int* __restrict__ ssrc)
{
    int e = blockIdx.x * 256 + threadIdx.x;
    if (e >= TOTE) return;
    int s, d;
    if (e < NE)          { s = ews[e];          d = ewd[e]; }
    else if (e < 2 * NE) { s = ecs[e - NE];     d = ecd[e - NE] + NPAP; }
    else                 { s = ers[e - 2 * NE]; d = erd[e - 2 * NE] + 2 * NPAP; }
    int shadow = (e >> 8) & 3;
    int pos = base4[shadow * N_SEG + d] + (int)rank16[e];
    ssrc[pos] = s;
}

// ---------- wave-per-segment fused softmax + fp8 gather ----------
__global__ __launch_bounds__(256) void han_seg(
    const int* __restrict__ starts, const int* __restrict__ ssrc,
    const float* __restrict__ a_sw, const float* __restrict__ a_dw,
    const float* __restrict__ a_sc, const float* __restrict__ a_dc,
    const float* __restrict__ a_sr, const float* __restrict__ a_dr,
    const unsigned* __restrict__ h8_a, const unsigned* __restrict__ h8_p,
    short* __restrict__ outall)
{
    int w = threadIdx.x >> 6, lane = threadIdx.x & 63;
    int n = blockIdx.x * 4 + w;
    if (n >= N_SEG) return;

    const float* asrc; const float* adst; const unsigned* h8;
    int nloc;
    if (n < NPAP)          { nloc = n;            asrc = a_sw; adst = a_dw; h8 = h8_a; }
    else if (n < 2 * NPAP) { nloc = n - NPAP;     asrc = a_sc; adst = a_dc; h8 = h8_p; }
    else                   { nloc = n - 2 * NPAP; asrc = a_sr; adst = a_dr; h8 = h8_p; }

    int hh = lane >> 3;
    int c0 = lane << 2;
    float ad = adst[nloc * 8 + hh];

    int i = starts[n], end = starts[n + 1];
    float ac0 = 0.f, ac1 = 0.f, ac2 = 0.f, ac3 = 0.f, ps = 0.f;

    for (; i + 4 <= end; i += 4) {
        int s0 = __builtin_amdgcn_readfirstlane(ssrc[i]);
        int s1 = __builtin_amdgcn_readfirstlane(ssrc[i + 1]);
        int s2 = __builtin_amdgcn_readfirstlane(ssrc[i + 2]);
        int s3 = __builtin_amdgcn_readfirstlane(ssrc[i + 3]);
        float x0 = asrc[s0 * 8 + hh] + ad;
        float x1 = asrc[s1 * 8 + hh] + ad;
        float x2 = asrc[s2 * 8 + hh] + ad;
        float x3 = asrc[s3 * 8 + hh] + ad;
        unsigned v0 = h8[s0 * 64 + lane];
        unsigned v1 = h8[s1 * 64 + lane];
        unsigned v2 = h8[s2 * 64 + lane];
        unsigned v3 = h8[s3 * 64 + lane];
        x0 = x0 > 0.f ? x0 : NEG_SLOPE * x0;
        x1 = x1 > 0.f ? x1 : NEG_SLOPE * x1;
        x2 = x2 > 0.f ? x2 : NEG_SLOPE * x2;
        x3 = x3 > 0.f ? x3 : NEG_SLOPE * x3;
        float e0 = __expf(x0), e1 = __expf(x1), e2 = __expf(x2), e3 = __expf(x3);
        ps += (e0 + e1) + (e2 + e3);
        ac0 += e0 * __builtin_amdgcn_cvt_f32_fp8(v0, 0) + e1 * __builtin_amdgcn_cvt_f32_fp8(v1, 0)
             + e2 * __builtin_amdgcn_cvt_f32_fp8(v2, 0) + e3 * __builtin_amdgcn_cvt_f32_fp8(v3, 0);
        ac1 += e0 * __builtin_amdgcn_cvt_f32_fp8(v0, 1) + e1 * __builtin_amdgcn_cvt_f32_fp8(v1, 1)
             + e2 * __builtin_amdgcn_cvt_f32_fp8(v2, 1) + e3 * __builtin_amdgcn_cvt_f32_fp8(v3, 1);
        ac2 += e0 * __builtin_amdgcn_cvt_f32_fp8(v0, 2) + e1 * __builtin_amdgcn_cvt_f32_fp8(v1, 2)
             + e2 * __builtin_amdgcn_cvt_f32_fp8(v2, 2) + e3 * __builtin_amdgcn_cvt_f32_fp8(v3, 2);
        ac3 += e0 * __builtin_amdgcn_cvt_f32_fp8(v0, 3) + e1 * __builtin_amdgcn_cvt_f32_fp8(v1, 3)
             + e2 * __builtin_amdgcn_cvt_f32_fp8(v2, 3) + e3 * __builtin_amdgcn_cvt_f32_fp8(v3, 3);
    }
    for (; i < end; ++i) {
        int s0 = __builtin_amdgcn_readfirstlane(ssrc[i]);
        float x0 = asrc[s0 * 8 + hh] + ad;
        unsigned v0 = h8[s0 * 64 + lane];
        x0 = x0 > 0.f ? x0 : NEG_SLOPE * x0;
        float e0 = __expf(x0);
        ps += e0;
        ac0 += e0 * __builtin_amdgcn_cvt_f32_fp8(v0, 0);
        ac1 += e0 * __builtin_amdgcn_cvt_f32_fp8(v0, 1);
        ac2 += e0 * __builtin_amdgcn_cvt_f32_fp8(v0, 2);
        ac3 += e0 * __builtin_amdgcn_cvt_f32_fp8(v0, 3);
    }

    float inv = 1.0f / (ps + 1e-16f);
    float o0 = ac0 * inv, o1 = ac1 * inv, o2 = ac2 * inv, o3 = ac3 * inv;
    short4 o;
    o.x = f2bf(o0 > 0.f ? o0 : 0.f);
    o.y = f2bf(o1 > 0.f ? o1 : 0.f);
    o.z = f2bf(o2 > 0.f ? o2 : 0.f);
    o.w = f2bf(o3 > 0.f ? o3 : 0.f);
    *reinterpret_cast<short4*>(&outall[(size_t)n * 256 + c0]) = o;
}

// ---------- column sums (LDS-free, full occupancy) ----------
__global__ void colsum3(const short* __restrict__ outall,
                        float* __restrict__ cw, float* __restrict__ cc,
                        float* __restrict__ cr)
{
    int t = threadIdx.x;
    int r0 = blockIdx.x * 32;
    int rend = r0 + 32 < N_SEG ? r0 + 32 : N_SEG;
    float s = 0.f;
    for (int r = r0; r < rend; ++r) s += bf2f(outall[(size_t)r * 256 + t]);
    float* cs = r0 < NPAP ? cw : (r0 < 2 * NPAP ? cc : cr);
    atomicAdd(&cs[t], s);
}

// ---------- semantic-score GEMM (bf16 A) ----------
__global__ __launch_bounds__(256) void gemm_score(
    const short* __restrict__ A0, const short* __restrict__ Wt, const float* __restrict__ kb,
    float* __restrict__ sAcc0, int N0, int nb0,
    const short* __restrict__ A1, float* __restrict__ sAcc1, int N1,
    const float* __restrict__ q)
{
    __shared__ short As[64][64];
    __shared__ short Ws[256][64];
    __shared__ float red[256];

    int bx = blockIdx.x;
    const short* A; float* sAcc; int N, row0;
    if (bx < nb0) { A = A0; sAcc = sAcc0; N = N0; row0 = bx * 64; }
    else          { A = A1; sAcc = sAcc1; N = N1; row0 = (bx - nb0) * 64; }

    int tid = threadIdx.x;
    int w = tid >> 6, l = tid & 63;
    int lr = l & 15, lh = l >> 4;
    int swz = (l & 7) << 3;

    f32x4 acc[4][4] = {};

    for (int k0 = 0; k0 < 256; k0 += 64) {
#pragma unroll
        for (int i = 0; i < 2; ++i) {
            int lin = tid + i * 256;
            int r = lin >> 3, kc = (lin & 7) << 3;
            bf16x8 v = {};
            int gr = row0 + r;
            if (gr < N) v = *reinterpret_cast<const bf16x8*>(&A[(size_t)gr * 256 + k0 + kc]);
            *reinterpret_cast<bf16x8*>(&As[r][kc ^ ((r & 7) << 3)]) = v;
        }
#pragma unroll
        for (int i = 0; i < 8; ++i) {
            int lin = tid + i * 256;
            int c = lin >> 3, kc = (lin & 7) << 3;
            *reinterpret_cast<bf16x8*>(&Ws[c][kc ^ ((c & 7) << 3)]) =
                *reinterpret_cast<const bf16x8*>(&Wt[(size_t)c * 256 + k0 + kc]);
        }
        __syncthreads();
#pragma unroll
        for (int kk = 0; kk < 64; kk += 32) {
            int krow = (kk + lh * 8) ^ swz;
            bf16x8 af[4], bfr[4];
#pragma unroll
            for (int mi = 0; mi < 4; ++mi)
                af[mi] = *reinterpret_cast<bf16x8*>(&As[mi * 16 + lr][krow]);
#pragma unroll
            for (int ni = 0; ni < 4; ++ni)
                bfr[ni] = *reinterpret_cast<bf16x8*>(&Ws[w * 64 + ni * 16 + lr][krow]);
#pragma unroll
            for (int mi = 0; mi < 4; ++mi)
#pragma unroll
                for (int ni = 0; ni < 4; ++ni)
                    acc[mi][ni] = __builtin_amdgcn_mfma_f32_16x16x32_bf16(
                        af[mi], bfr[ni], acc[mi][ni], 0, 0, 0);
        }
        __syncthreads();
    }

    float s = 0.f;
#pragma unroll
    for (int mi = 0; mi < 4; ++mi) {
        int rb = row0 + mi * 16 + lh * 4;
#pragma unroll
        for (int ni = 0; ni < 4; ++ni) {
            int c = w * 64 + ni * 16 + lr;
            float bc = kb[c], qc = q[c];
#pragma unroll
            for (int j = 0; j < 4; ++j) {
                if (rb + j < N) s += tanhf(acc[mi][ni][j] + bc) * qc;
            }
        }
    }
    red[tid] = s;
    __syncthreads();
    for (int k = 128; k > 0; k >>= 1) {
        if (tid < k) red[tid] += red[tid + k];
        __syncthreads();
    }
    if (tid == 0) atomicAdd(sAcc, red[0]);
}

// ---------- finalize ----------
__global__ void finalize(const float* __restrict__ scoreAcc,
                         const float* __restrict__ colsum_w, const float* __restrict__ colsum_c,
                         const float* __restrict__ colsum_r,
                         const float* __restrict__ lin_W, const float* __restrict__ lin_b,
                         float* __restrict__ out)
{
    int t = threadIdx.x;
    if (t >= 32) return;
    float sw = scoreAcc[0] / (float)NPAP;
    float scs = scoreAcc[1] / (float)NPAP;
    float mx = fmaxf(sw, scs);
    float ew = expf(sw - mx), ec = expf(scs - mx);
    float aw = ew / (ew + ec), ac = ec / (ew + ec);
    int row = t >> 4, j = t & 15;
    float acc = lin_b[j];
    for (int c = 0; c < 256; ++c) {
        float p = (row == 0) ? colsum_r[c] : (aw * colsum_w[c] + ac * colsum_c[c]);
        acc += p * lin_W[c * 16 + j];
    }
    out[row * 16 + j] = acc;
}

extern "C" void kernel_launch(void* const* d_in, const int* in_sizes, int n_in,
                              void* d_out, int out_size, void* d_ws, size_t ws_size,
                              hipStream_t stream)
{
    const float* x_a   = (const float*)d_in[0];
    const float* x_p   = (const float*)d_in[1];
    const float* W_a   = (const float*)d_in[2];
    const float* b_a   = (const float*)d_in[3];
    const float* W_p   = (const float*)d_in[4];
    const float* b_p   = (const float*)d_in[5];
    const float* att_sw = (const float*)d_in[6];
    const float* att_dw = (const float*)d_in[7];
    const float* att_sc = (const float*)d_in[8];
    const float* att_dc = (const float*)d_in[9];
    const float* att_sr = (const float*)d_in[10];
    const float* att_dr = (const float*)d_in[11];
    const float* k_W   = (const float*)d_in[12];
    const float* k_b   = (const float*)d_in[13];
    const float* q     = (const float*)d_in[14];
    const float* lin_W = (const float*)d_in[15];
    const float* lin_b = (const float*)d_in[16];
    const int* ew_src = (const int*)d_in[17];
    const int* ew_dst = (const int*)d_in[18];
    const int* ec_src = (const int*)d_in[19];
    const int* ec_dst = (const int*)d_in[20];
    const int* er_src = (const int*)d_in[21];
    const int* er_dst = (const int*)d_in[22];

    float* ws = (float*)d_ws;
    size_t off = 0;
    auto align4 = [&]() { off = (off + 3) & ~(size_t)3; };

    short* h_a_bf = (short*)(ws + off); off += (size_t)NA * HID / 2;
    short* h_p_bf = (short*)(ws + off); off += (size_t)NPAP * HID / 2;
    unsigned char* h8_a = (unsigned char*)(ws + off); off += (size_t)NA * HID / 4;
    unsigned char* h8_p = (unsigned char*)(ws + off); off += (size_t)NPAP * HID / 4;
    short* WaT  = (short*)(ws + off); off += 256 * 256 / 2;
    short* WpT  = (short*)(ws + off); off += 256 * 256 / 2;
    short* kWT  = (short*)(ws + off); off += 256 * 256 / 2;
    float* a_sw = ws + off; off += (size_t)NA * 8;
    float* a_dw = ws + off; off += (size_t)NPAP * 8;
    float* a_sc = ws + off; off += (size_t)NPAP * 8;
    float* a_dc = ws + off; off += (size_t)NPAP * 8;
    float* a_sr = ws + off; off += (size_t)NPAP * 8;
    float* a_dr = ws + off; off += (size_t)NA * 8;
    short* outall = (short*)(ws + off); off += (size_t)N_SEG * HID / 2;
    // CSR scratch
    int* starts  = (int*)(ws + off); off += N_SEG + 1; align4();
    int* base4   = (int*)(ws + off); off += 4 * N_SEG; align4();
    int* sexcl   = (int*)(ws + off); off += N_SEG + 1; align4();
    int* sbsum   = (int*)(ws + off); off += 256;
    int* sboff   = (int*)(ws + off); off += 256;
    int* ssrc    = (int*)(ws + off); off += TOTE;
    unsigned short* rank16 = (unsigned short*)(ws + off); off += TOTE / 2;
    // zeroed-per-call region: deg4 + colsums + score
    size_t zero_start = off;
    int* deg4       = (int*)(ws + off); off += 4 * N_SEG; align4();
    float* colsum_w = ws + off; off += 256;
    float* colsum_c = ws + off; off += 256;
    float* colsum_r = ws + off; off += 256;
    float* score    = ws + off; off += 2;
    size_t zero_bytes = (off - zero_start) * sizeof(float);

    hipMemsetAsync(ws + zero_start, 0, zero_bytes, stream);

    // 1. weight transposes
    wconv<<<48, 256, 0, stream>>>(W_a, WaT, W_p, WpT, k_W, kWT);

    // 2. projection GEMMs (16KB-LDS 64x64 tiles) ∪ deg-count+rank
    proj_deg<<<PROJ_BLKS + DEG_BLKS, 256, 0, stream>>>(
        x_a, WaT, b_a, h_a_bf, h8_a,
        x_p, WpT, b_p, h_p_bf, h8_p,
        ew_dst, ec_dst, er_dst, deg4, rank16);

    // 3. attention dots ∪ scan level-1
    natt_scan<<<NATT_BLKS + NBS, 256, 0, stream>>>(
        h_p_bf, h_a_bf, att_dw, att_sc, att_dc, att_sr, att_sw, att_dr,
        a_dw, a_sc, a_dc, a_sr, a_sw, a_dr,
        deg4, sexcl, sbsum);

    // 4-5. scan levels 2, 3
    scan_l2<<<1, 256, 0, stream>>>(sbsum, sboff, NBS);
    scan_l3<<<(N_SEG + 1 + 255) / 256, 256, 0, stream>>>(sexcl, sboff, deg4, starts, base4, N_SEG);

    // 6. atomic-free edge scatter
    scatter_edges<<<(TOTE + 255) / 256, 256, 0, stream>>>(ew_src, ew_dst, ec_src, ec_dst,
                                                          er_src, er_dst, base4, rank16, ssrc);

    // 7. wave-per-segment attention aggregate (fp8 gather)
    han_seg<<<(N_SEG + 3) / 4, 256, 0, stream>>>(starts, ssrc, a_sw, a_dw, a_sc, a_dc, a_sr, a_dr,
                                                 (const unsigned*)h8_a, (const unsigned*)h8_p,
                                                 outall);

    // 8. column sums (LDS-free) + semantic scores (separate kernels — LDS isolation)
    colsum3<<<(N_SEG + 31) / 32, 256, 0, stream>>>(outall, colsum_w, colsum_c, colsum_r);
    gemm_score<<<2 * NBP, 256, 0, stream>>>(
        outall, kWT, k_b, score + 0, NPAP, NBP,
        outall + (size_t)NPAP * HID, score + 1, NPAP, q);

    // 9. finalize
    finalize<<<1, 64, 0, stream>>>(score, colsum_w, colsum_c, colsum_r, lin_W, lin_b, (float*)d_out);
}

// Round 16
// 228.714 us; speedup vs baseline: 1.0748x; 1.0748x over previous
//
#include <hip/hip_runtime.h>
#include <hip/hip_bf16.h>

#define HEADS 8
#define HID 256
#define NA 10000
#define NPAP 20000
#define NE 256000
#define N_SEG (2 * NPAP + NA)     // combined segments: writes(20k) | cites(20k) | rev(10k)
#define TOTE (3 * NE)             // combined edges
#define NEG_SLOPE 0.2f
#define NBA 157                   // (NA+63)/64
#define NBP 313                   // (NPAP+63)/64
#define PROJ_BLKS (NBA + NBP)     // 470  (256-wide tiles, 40KB LDS — R14 proven)
#define DEG_BLKS 3000             // TOTE/256
#define NATT_BLKS (NPAP + NA)     // 30000
#define NBS ((N_SEG + 255) / 256) // 196

typedef __attribute__((ext_vector_type(8))) short bf16x8;
typedef __attribute__((ext_vector_type(4))) float f32x4;

// ---------- f32 <-> bf16 helpers ----------
__device__ __forceinline__ short f2bf(float x) {
    unsigned u = __float_as_uint(x);
    unsigned r = (u + 0x7fffu + ((u >> 16) & 1u)) >> 16;   // RNE
    return (short)r;
}
__device__ __forceinline__ float bf2f(short s) {
    return __uint_as_float(((unsigned)(unsigned short)s) << 16);
}

// ---------- weight transposes: Wt[c][k] = bf16(W[k][c]) ----------
__global__ __launch_bounds__(256) void wconv(
    const float* __restrict__ W_a, short* __restrict__ WaT,
    const float* __restrict__ W_p, short* __restrict__ WpT,
    const float* __restrict__ k_W, short* __restrict__ kWT)
{
    __shared__ short T[64][65];
    int b = blockIdx.x;
    int t = threadIdx.x;
    int z = b >> 4, rem = b & 15;
    int k0 = (rem & 3) * 64, c0 = (rem >> 2) * 64;
    const float* W = z == 0 ? W_a : (z == 1 ? W_p : k_W);
    short* Wt      = z == 0 ? WaT : (z == 1 ? WpT : kWT);
    int rr = t >> 6, c = t & 63;
#pragma unroll
    for (int p = 0; p < 16; ++p) {
        int r = rr + p * 4;
        T[c][r] = f2bf(W[(size_t)(k0 + r) * 256 + c0 + c]);
    }
    __syncthreads();
#pragma unroll
    for (int p = 0; p < 16; ++p) {
        int cc = rr + p * 4;
        Wt[(size_t)(c0 + cc) * 256 + k0 + c] = T[cc][c];
    }
}

// ---------- fused: projection GEMMs (256-wide, 40KB LDS — R14) ∪ deg-count+rank ----------
// shadow(e) = (e>>8)&3 — matches scatter_edges.
__global__ __launch_bounds__(256) void proj_deg(
    const float* __restrict__ A0, const short* __restrict__ Wt0, const float* __restrict__ b0,
    short* __restrict__ C0, unsigned char* __restrict__ H80,
    const float* __restrict__ A1, const short* __restrict__ Wt1, const float* __restrict__ b1,
    short* __restrict__ C1, unsigned char* __restrict__ H81,
    const int* __restrict__ ewd, const int* __restrict__ ecd, const int* __restrict__ erd,
    int* __restrict__ deg4, unsigned short* __restrict__ rank16)
{
    __shared__ short As[64][64];
    __shared__ short Ws[256][64];

    int b = blockIdx.x;
    int t = threadIdx.x;

    if (b >= PROJ_BLKS) {
        // ---- deg + rank region ----
        int bb = b - PROJ_BLKS;
        int e = bb * 256 + t;
        if (e >= TOTE) return;
        int d;
        if (e < NE)          d = ewd[e];
        else if (e < 2 * NE) d = ecd[e - NE] + NPAP;
        else                 d = erd[e - 2 * NE] + 2 * NPAP;
        int r = atomicAdd(&deg4[(bb & 3) * N_SEG + d], 1);
        rank16[e] = (unsigned short)r;
        return;
    }

    // ---- projection GEMM region: 64 rows x 256 cols per block ----
    const float* A; const short* Wt; const float* bias; short* Cb; unsigned char* H8; int N, row0;
    if (b < NBA) { A = A0; Wt = Wt0; bias = b0; Cb = C0; H8 = H80; N = NA;   row0 = b * 64; }
    else         { A = A1; Wt = Wt1; bias = b1; Cb = C1; H8 = H81; N = NPAP; row0 = (b - NBA) * 64; }

    int w = t >> 6, l = t & 63;
    int lr = l & 15, lh = l >> 4;
    int swz = (l & 7) << 3;

    f32x4 acc[4][4] = {};

    for (int k0 = 0; k0 < 256; k0 += 64) {
#pragma unroll
        for (int i = 0; i < 4; ++i) {
            int lin = t + i * 256;
            int r = lin >> 4, fc = (lin & 15) << 2;
            float4 v = make_float4(0.f, 0.f, 0.f, 0.f);
            int gr = row0 + r;
            if (gr < N) v = *reinterpret_cast<const float4*>(&A[(size_t)gr * 256 + k0 + fc]);
            short4 o;
            o.x = f2bf(v.x); o.y = f2bf(v.y); o.z = f2bf(v.z); o.w = f2bf(v.w);
            *reinterpret_cast<short4*>(&As[r][fc ^ ((r & 7) << 3)]) = o;
        }
#pragma unroll
        for (int i = 0; i < 8; ++i) {
            int lin = t + i * 256;
            int c = lin >> 3, kc = (lin & 7) << 3;
            *reinterpret_cast<bf16x8*>(&Ws[c][kc ^ ((c & 7) << 3)]) =
                *reinterpret_cast<const bf16x8*>(&Wt[(size_t)c * 256 + k0 + kc]);
        }
        __syncthreads();
#pragma unroll
        for (int kk = 0; kk < 64; kk += 32) {
            int krow = (kk + lh * 8) ^ swz;
            bf16x8 af[4], bfr[4];
#pragma unroll
            for (int mi = 0; mi < 4; ++mi)
                af[mi] = *reinterpret_cast<bf16x8*>(&As[mi * 16 + lr][krow]);
#pragma unroll
            for (int ni = 0; ni < 4; ++ni)
                bfr[ni] = *reinterpret_cast<bf16x8*>(&Ws[w * 64 + ni * 16 + lr][krow]);
#pragma unroll
            for (int mi = 0; mi < 4; ++mi)
#pragma unroll
                for (int ni = 0; ni < 4; ++ni)
                    acc[mi][ni] = __builtin_amdgcn_mfma_f32_16x16x32_bf16(
                        af[mi], bfr[ni], acc[mi][ni], 0, 0, 0);
        }
        __syncthreads();
    }

#pragma unroll
    for (int mi = 0; mi < 4; ++mi) {
        int rb = row0 + mi * 16 + lh * 4;
#pragma unroll
        for (int ni = 0; ni < 4; ++ni) {
            int c = w * 64 + ni * 16 + lr;
            float bc = bias[c];
#pragma unroll
            for (int j = 0; j < 4; ++j) {
                if (rb + j < N) {
                    float v = acc[mi][ni][j] + bc;
                    Cb[(size_t)(rb + j) * 256 + c] = f2bf(v);
                    unsigned pk = __builtin_amdgcn_cvt_pk_fp8_f32(v, v, 0, false);
                    H8[(size_t)(rb + j) * 256 + c] = (unsigned char)pk;
                }
            }
        }
    }
}

// ---------- fused: per-node attention dots ∪ scan level-1 ----------
__global__ __launch_bounds__(256) void natt_scan(
    const short* __restrict__ h_p, const short* __restrict__ h_a,
    const float* __restrict__ att_dw, const float* __restrict__ att_sc,
    const float* __restrict__ att_dc, const float* __restrict__ att_sr,
    const float* __restrict__ att_sw, const float* __restrict__ att_dr,
    float* __restrict__ a_dw, float* __restrict__ a_sc,
    float* __restrict__ a_dc, float* __restrict__ a_sr,
    float* __restrict__ a_sw, float* __restrict__ a_dr,
    const int* __restrict__ deg4, int* __restrict__ excl, int* __restrict__ bsum)
{
    int b = blockIdx.x;
    int t = threadIdx.x;

    if (b >= NATT_BLKS) {
        __shared__ int buf[256];
        int bb = b - NATT_BLKS;
        int idx = bb * 256 + t;
        int v = 0;
        if (idx < N_SEG)
            v = deg4[idx] + deg4[N_SEG + idx] + deg4[2 * N_SEG + idx] + deg4[3 * N_SEG + idx];
        buf[t] = v;
        __syncthreads();
        for (int off = 1; off < 256; off <<= 1) {
            int add = (t >= off) ? buf[t - off] : 0;
            __syncthreads();
            buf[t] += add;
            __syncthreads();
        }
        if (idx < N_SEG) excl[idx] = buf[t] - v;
        if (t == 255) bsum[bb] = buf[255];
        return;
    }

    if (b < NPAP) {
        float v = bf2f(h_p[(size_t)b * 256 + t]);
        float d0 = v * att_dw[t], d1 = v * att_sc[t], d2 = v * att_dc[t], d3 = v * att_sr[t];
#pragma unroll
        for (int k = 16; k > 0; k >>= 1) {
            d0 += __shfl_xor(d0, k, 64);
            d1 += __shfl_xor(d1, k, 64);
            d2 += __shfl_xor(d2, k, 64);
            d3 += __shfl_xor(d3, k, 64);
        }
        if ((t & 31) == 0) {
            int hh = t >> 5;
            a_dw[b * 8 + hh] = d0; a_sc[b * 8 + hh] = d1;
            a_dc[b * 8 + hh] = d2; a_sr[b * 8 + hh] = d3;
        }
    } else {
        int m = b - NPAP;
        float v = bf2f(h_a[(size_t)m * 256 + t]);
        float d0 = v * att_sw[t], d1 = v * att_dr[t];
#pragma unroll
        for (int k = 16; k > 0; k >>= 1) {
            d0 += __shfl_xor(d0, k, 64);
            d1 += __shfl_xor(d1, k, 64);
        }
        if ((t & 31) == 0) {
            int hh = t >> 5;
            a_sw[m * 8 + hh] = d0; a_dr[m * 8 + hh] = d1;
        }
    }
}

// ---------- scan level-2 ----------
__global__ void scan_l2(const int* __restrict__ bsum, int* __restrict__ boff, int nb)
{
    __shared__ int buf[256];
    int t = threadIdx.x;
    int v = (t < nb) ? bsum[t] : 0;
    buf[t] = v;
    __syncthreads();
    for (int off = 1; off < 256; off <<= 1) {
        int add = (t >= off) ? buf[t - off] : 0;
        __syncthreads();
        buf[t] += add;
        __syncthreads();
    }
    if (t < nb) boff[t] = buf[t] - v;
}

// L3: starts + 4 shadow bases
__global__ void scan_l3(const int* __restrict__ excl, const int* __restrict__ boff,
                        const int* __restrict__ deg4,
                        int* __restrict__ starts, int* __restrict__ base4, int N)
{
    int i = blockIdx.x * 256 + threadIdx.x;
    if (i > N) return;
    int v = (i == N) ? TOTE : excl[i] + boff[i >> 8];
    starts[i] = v;
    if (i < N) {
        int c = v;
        base4[i] = c;                 c += deg4[i];
        base4[N_SEG + i] = c;         c += deg4[N_SEG + i];
        base4[2 * N_SEG + i] = c;     c += deg4[2 * N_SEG + i];
        base4[3 * N_SEG + i] = c;
    }
}

// ---------- edge scatter: NO atomics ----------
__global__ __launch_bounds__(256) void scatter_edges(
    const int* __restrict__ ews, const int* __restrict__ ewd,
    const int* __restrict__ ecs, const int* __restrict__ ecd,
    const int* __restrict__ ers, const int* __restrict__ erd,
    const int* __restrict__ base4, const unsigned short* __restrict__ rank16,
    int* __restrict__ ssrc)
{
    int e = blockIdx.x * 256 + threadIdx.x;
    if (e >= TOTE) return;
    int s, d;
    if (e < NE)          { s = ews[e];          d = ewd[e]; }
    else if (e < 2 * NE) { s = ecs[e - NE];     d = ecd[e - NE] + NPAP; }
    else                 { s = ers[e - 2 * NE]; d = erd[e - 2 * NE] + 2 * NPAP; }
    int shadow = (e >> 8) & 3;
    int pos = base4[shadow * N_SEG + d] + (int)rank16[e];
    ssrc[pos] = s;
}

// ---------- wave-per-segment fused softmax + fp8 gather ----------
__global__ __launch_bounds__(256) void han_seg(
    const int* __restrict__ starts, const int* __restrict__ ssrc,
    const float* __restrict__ a_sw, const float* __restrict__ a_dw,
    const float* __restrict__ a_sc, const float* __restrict__ a_dc,
    const float* __restrict__ a_sr, const float* __restrict__ a_dr,
    const unsigned* __restrict__ h8_a, const unsigned* __restrict__ h8_p,
    short* __restrict__ outall)
{
    int w = threadIdx.x >> 6, lane = threadIdx.x & 63;
    int n = blockIdx.x * 4 + w;
    if (n >= N_SEG) return;

    const float* asrc; const float* adst; const unsigned* h8;
    int nloc;
    if (n < NPAP)          { nloc = n;            asrc = a_sw; adst = a_dw; h8 = h8_a; }
    else if (n < 2 * NPAP) { nloc = n - NPAP;     asrc = a_sc; adst = a_dc; h8 = h8_p; }
    else                   { nloc = n - 2 * NPAP; asrc = a_sr; adst = a_dr; h8 = h8_p; }

    int hh = lane >> 3;
    int c0 = lane << 2;
    float ad = adst[nloc * 8 + hh];

    int i = starts[n], end = starts[n + 1];
    float ac0 = 0.f, ac1 = 0.f, ac2 = 0.f, ac3 = 0.f, ps = 0.f;

    for (; i + 4 <= end; i += 4) {
        int s0 = __builtin_amdgcn_readfirstlane(ssrc[i]);
        int s1 = __builtin_amdgcn_readfirstlane(ssrc[i + 1]);
        int s2 = __builtin_amdgcn_readfirstlane(ssrc[i + 2]);
        int s3 = __builtin_amdgcn_readfirstlane(ssrc[i + 3]);
        float x0 = asrc[s0 * 8 + hh] + ad;
        float x1 = asrc[s1 * 8 + hh] + ad;
        float x2 = asrc[s2 * 8 + hh] + ad;
        float x3 = asrc[s3 * 8 + hh] + ad;
        unsigned v0 = h8[s0 * 64 + lane];
        unsigned v1 = h8[s1 * 64 + lane];
        unsigned v2 = h8[s2 * 64 + lane];
        unsigned v3 = h8[s3 * 64 + lane];
        x0 = x0 > 0.f ? x0 : NEG_SLOPE * x0;
        x1 = x1 > 0.f ? x1 : NEG_SLOPE * x1;
        x2 = x2 > 0.f ? x2 : NEG_SLOPE * x2;
        x3 = x3 > 0.f ? x3 : NEG_SLOPE * x3;
        float e0 = __expf(x0), e1 = __expf(x1), e2 = __expf(x2), e3 = __expf(x3);
        ps += (e0 + e1) + (e2 + e3);
        ac0 += e0 * __builtin_amdgcn_cvt_f32_fp8(v0, 0) + e1 * __builtin_amdgcn_cvt_f32_fp8(v1, 0)
             + e2 * __builtin_amdgcn_cvt_f32_fp8(v2, 0) + e3 * __builtin_amdgcn_cvt_f32_fp8(v3, 0);
        ac1 += e0 * __builtin_amdgcn_cvt_f32_fp8(v0, 1) + e1 * __builtin_amdgcn_cvt_f32_fp8(v1, 1)
             + e2 * __builtin_amdgcn_cvt_f32_fp8(v2, 1) + e3 * __builtin_amdgcn_cvt_f32_fp8(v3, 1);
        ac2 += e0 * __builtin_amdgcn_cvt_f32_fp8(v0, 2) + e1 * __builtin_amdgcn_cvt_f32_fp8(v1, 2)
             + e2 * __builtin_amdgcn_cvt_f32_fp8(v2, 2) + e3 * __builtin_amdgcn_cvt_f32_fp8(v3, 2);
        ac3 += e0 * __builtin_amdgcn_cvt_f32_fp8(v0, 3) + e1 * __builtin_amdgcn_cvt_f32_fp8(v1, 3)
             + e2 * __builtin_amdgcn_cvt_f32_fp8(v2, 3) + e3 * __builtin_amdgcn_cvt_f32_fp8(v3, 3);
    }
    for (; i < end; ++i) {
        int s0 = __builtin_amdgcn_readfirstlane(ssrc[i]);
        float x0 = asrc[s0 * 8 + hh] + ad;
        unsigned v0 = h8[s0 * 64 + lane];
        x0 = x0 > 0.f ? x0 : NEG_SLOPE * x0;
        float e0 = __expf(x0);
        ps += e0;
        ac0 += e0 * __builtin_amdgcn_cvt_f32_fp8(v0, 0);
        ac1 += e0 * __builtin_amdgcn_cvt_f32_fp8(v0, 1);
        ac2 += e0 * __builtin_amdgcn_cvt_f32_fp8(v0, 2);
        ac3 += e0 * __builtin_amdgcn_cvt_f32_fp8(v0, 3);
    }

    float inv = 1.0f / (ps + 1e-16f);
    float o0 = ac0 * inv, o1 = ac1 * inv, o2 = ac2 * inv, o3 = ac3 * inv;
    short4 o;
    o.x = f2bf(o0 > 0.f ? o0 : 0.f);
    o.y = f2bf(o1 > 0.f ? o1 : 0.f);
    o.z = f2bf(o2 > 0.f ? o2 : 0.f);
    o.w = f2bf(o3 > 0.f ? o3 : 0.f);
    *reinterpret_cast<short4*>(&outall[(size_t)n * 256 + c0]) = o;
}

// ---------- column sums (LDS-free, full occupancy) ----------
__global__ void colsum3(const short* __restrict__ outall,
                        float* __restrict__ cw, float* __restrict__ cc,
                        float* __restrict__ cr)
{
    int t = threadIdx.x;
    int r0 = blockIdx.x * 32;
    int rend = r0 + 32 < N_SEG ? r0 + 32 : N_SEG;
    float s = 0.f;
    for (int r = r0; r < rend; ++r) s += bf2f(outall[(size_t)r * 256 + t]);
    float* cs = r0 < NPAP ? cw : (r0 < 2 * NPAP ? cc : cr);
    atomicAdd(&cs[t], s);
}

// ---------- semantic-score GEMM (bf16 A) ----------
__global__ __launch_bounds__(256) void gemm_score(
    const short* __restrict__ A0, const short* __restrict__ Wt, const float* __restrict__ kb,
    float* __restrict__ sAcc0, int N0, int nb0,
    const short* __restrict__ A1, float* __restrict__ sAcc1, int N1,
    const float* __restrict__ q)
{
    __shared__ short As[64][64];
    __shared__ short Ws[256][64];
    __shared__ float red[256];

    int bx = blockIdx.x;
    const short* A; float* sAcc; int N, row0;
    if (bx < nb0) { A = A0; sAcc = sAcc0; N = N0; row0 = bx * 64; }
    else          { A = A1; sAcc = sAcc1; N = N1; row0 = (bx - nb0) * 64; }

    int tid = threadIdx.x;
    int w = tid >> 6, l = tid & 63;
    int lr = l & 15, lh = l >> 4;
    int swz = (l & 7) << 3;

    f32x4 acc[4][4] = {};

    for (int k0 = 0; k0 < 256; k0 += 64) {
#pragma unroll
        for (int i = 0; i < 2; ++i) {
            int lin = tid + i * 256;
            int r = lin >> 3, kc = (lin & 7) << 3;
            bf16x8 v = {};
            int gr = row0 + r;
            if (gr < N) v = *reinterpret_cast<const bf16x8*>(&A[(size_t)gr * 256 + k0 + kc]);
            *reinterpret_cast<bf16x8*>(&As[r][kc ^ ((r & 7) << 3)]) = v;
        }
#pragma unroll
        for (int i = 0; i < 8; ++i) {
            int lin = tid + i * 256;
            int c = lin >> 3, kc = (lin & 7) << 3;
            *reinterpret_cast<bf16x8*>(&Ws[c][kc ^ ((c & 7) << 3)]) =
                *reinterpret_cast<const bf16x8*>(&Wt[(size_t)c * 256 + k0 + kc]);
        }
        __syncthreads();
#pragma unroll
        for (int kk = 0; kk < 64; kk += 32) {
            int krow = (kk + lh * 8) ^ swz;
            bf16x8 af[4], bfr[4];
#pragma unroll
            for (int mi = 0; mi < 4; ++mi)
                af[mi] = *reinterpret_cast<bf16x8*>(&As[mi * 16 + lr][krow]);
#pragma unroll
            for (int ni = 0; ni < 4; ++ni)
                bfr[ni] = *reinterpret_cast<bf16x8*>(&Ws[w * 64 + ni * 16 + lr][krow]);
#pragma unroll
            for (int mi = 0; mi < 4; ++mi)
#pragma unroll
                for (int ni = 0; ni < 4; ++ni)
                    acc[mi][ni] = __builtin_amdgcn_mfma_f32_16x16x32_bf16(
                        af[mi], bfr[ni], acc[mi][ni], 0, 0, 0);
        }
        __syncthreads();
    }

    float s = 0.f;
#pragma unroll
    for (int mi = 0; mi < 4; ++mi) {
        int rb = row0 + mi * 16 + lh * 4;
#pragma unroll
        for (int ni = 0; ni < 4; ++ni) {
            int c = w * 64 + ni * 16 + lr;
            float bc = kb[c], qc = q[c];
#pragma unroll
            for (int j = 0; j < 4; ++j) {
                if (rb + j < N) s += tanhf(acc[mi][ni][j] + bc) * qc;
            }
        }
    }
    red[tid] = s;
    __syncthreads();
    for (int k = 128; k > 0; k >>= 1) {
        if (tid < k) red[tid] += red[tid + k];
        __syncthreads();
    }
    if (tid == 0) atomicAdd(sAcc, red[0]);
}

// ---------- finalize ----------
__global__ void finalize(const float* __restrict__ scoreAcc,
                         const float* __restrict__ colsum_w, const float* __restrict__ colsum_c,
                         const float* __restrict__ colsum_r,
                         const float* __restrict__ lin_W, const float* __restrict__ lin_b,
                         float* __restrict__ out)
{
    int t = threadIdx.x;
    if (t >= 32) return;
    float sw = scoreAcc[0] / (float)NPAP;
    float scs = scoreAcc[1] / (float)NPAP;
    float mx = fmaxf(sw, scs);
    float ew = expf(sw - mx), ec = expf(scs - mx);
    float aw = ew / (ew + ec), ac = ec / (ew + ec);
    int row = t >> 4, j = t & 15;
    float acc = lin_b[j];
    for (int c = 0; c < 256; ++c) {
        float p = (row == 0) ? colsum_r[c] : (aw * colsum_w[c] + ac * colsum_c[c]);
        acc += p * lin_W[c * 16 + j];
    }
    out[row * 16 + j] = acc;
}

extern "C" void kernel_launch(void* const* d_in, const int* in_sizes, int n_in,
                              void* d_out, int out_size, void* d_ws, size_t ws_size,
                              hipStream_t stream)
{
    const float* x_a   = (const float*)d_in[0];
    const float* x_p   = (const float*)d_in[1];
    const float* W_a   = (const float*)d_in[2];
    const float* b_a   = (const float*)d_in[3];
    const float* W_p   = (const float*)d_in[4];
    const float* b_p   = (const float*)d_in[5];
    const float* att_sw = (const float*)d_in[6];
    const float* att_dw = (const float*)d_in[7];
    const float* att_sc = (const float*)d_in[8];
    const float* att_dc = (const float*)d_in[9];
    const float* att_sr = (const float*)d_in[10];
    const float* att_dr = (const float*)d_in[11];
    const float* k_W   = (const float*)d_in[12];
    const float* k_b   = (const float*)d_in[13];
    const float* q     = (const float*)d_in[14];
    const float* lin_W = (const float*)d_in[15];
    const float* lin_b = (const float*)d_in[16];
    const int* ew_src = (const int*)d_in[17];
    const int* ew_dst = (const int*)d_in[18];
    const int* ec_src = (const int*)d_in[19];
    const int* ec_dst = (const int*)d_in[20];
    const int* er_src = (const int*)d_in[21];
    const int* er_dst = (const int*)d_in[22];

    float* ws = (float*)d_ws;
    size_t off = 0;
    auto align4 = [&]() { off = (off + 3) & ~(size_t)3; };

    short* h_a_bf = (short*)(ws + off); off += (size_t)NA * HID / 2;
    short* h_p_bf = (short*)(ws + off); off += (size_t)NPAP * HID / 2;
    unsigned char* h8_a = (unsigned char*)(ws + off); off += (size_t)NA * HID / 4;
    unsigned char* h8_p = (unsigned char*)(ws + off); off += (size_t)NPAP * HID / 4;
    short* WaT  = (short*)(ws + off); off += 256 * 256 / 2;
    short* WpT  = (short*)(ws + off); off += 256 * 256 / 2;
    short* kWT  = (short*)(ws + off); off += 256 * 256 / 2;
    float* a_sw = ws + off; off += (size_t)NA * 8;
    float* a_dw = ws + off; off += (size_t)NPAP * 8;
    float* a_sc = ws + off; off += (size_t)NPAP * 8;
    float* a_dc = ws + off; off += (size_t)NPAP * 8;
    float* a_sr = ws + off; off += (size_t)NPAP * 8;
    float* a_dr = ws + off; off += (size_t)NA * 8;
    short* outall = (short*)(ws + off); off += (size_t)N_SEG * HID / 2;
    // CSR scratch
    int* starts  = (int*)(ws + off); off += N_SEG + 1; align4();
    int* base4   = (int*)(ws + off); off += 4 * N_SEG; align4();
    int* sexcl   = (int*)(ws + off); off += N_SEG + 1; align4();
    int* sbsum   = (int*)(ws + off); off += 256;
    int* sboff   = (int*)(ws + off); off += 256;
    int* ssrc    = (int*)(ws + off); off += TOTE;
    unsigned short* rank16 = (unsigned short*)(ws + off); off += TOTE / 2;
    // zeroed-per-call region: deg4 + colsums + score
    size_t zero_start = off;
    int* deg4       = (int*)(ws + off); off += 4 * N_SEG; align4();
    float* colsum_w = ws + off; off += 256;
    float* colsum_c = ws + off; off += 256;
    float* colsum_r = ws + off; off += 256;
    float* score    = ws + off; off += 2;
    size_t zero_bytes = (off - zero_start) * sizeof(float);

    hipMemsetAsync(ws + zero_start, 0, zero_bytes, stream);

    // 1. weight transposes
    wconv<<<48, 256, 0, stream>>>(W_a, WaT, W_p, WpT, k_W, kWT);

    // 2. projection GEMMs (R14 256-wide tiles) ∪ deg-count+rank
    proj_deg<<<PROJ_BLKS + DEG_BLKS, 256, 0, stream>>>(
        x_a, WaT, b_a, h_a_bf, h8_a,
        x_p, WpT, b_p, h_p_bf, h8_p,
        ew_dst, ec_dst, er_dst, deg4, rank16);

    // 3. attention dots ∪ scan level-1
    natt_scan<<<NATT_BLKS + NBS, 256, 0, stream>>>(
        h_p_bf, h_a_bf, att_dw, att_sc, att_dc, att_sr, att_sw, att_dr,
        a_dw, a_sc, a_dc, a_sr, a_sw, a_dr,
        deg4, sexcl, sbsum);

    // 4-5. scan levels 2, 3
    scan_l2<<<1, 256, 0, stream>>>(sbsum, sboff, NBS);
    scan_l3<<<(N_SEG + 1 + 255) / 256, 256, 0, stream>>>(sexcl, sboff, deg4, starts, base4, N_SEG);

    // 6. atomic-free edge scatter
    scatter_edges<<<(TOTE + 255) / 256, 256, 0, stream>>>(ew_src, ew_dst, ec_src, ec_dst,
                                                          er_src, er_dst, base4, rank16, ssrc);

    // 7. wave-per-segment attention aggregate (fp8 gather)
    han_seg<<<(N_SEG + 3) / 4, 256, 0, stream>>>(starts, ssrc, a_sw, a_dw, a_sc, a_dc, a_sr, a_dr,
                                                 (const unsigned*)h8_a, (const unsigned*)h8_p,
                                                 outall);

    // 8. column sums + semantic scores (separate kernels — LDS isolation)
    colsum3<<<(N_SEG + 31) / 32, 256, 0, stream>>>(outall, colsum_w, colsum_c, colsum_r);
    gemm_score<<<2 * NBP, 256, 0, stream>>>(
        outall, kWT, k_b, score + 0, NPAP, NBP,
        outall + (size_t)NPAP * HID, score + 1, NPAP, q);

    // 9. finalize
    finalize<<<1, 64, 0, stream>>>(score, colsum_w, colsum_c, colsum_r, lin_W, lin_b, (float*)d_out);
}